// Round 4
// baseline (93.181 us; speedup 1.0000x reference)
//
#include <hip/hip_runtime.h>
#include <cstdint>

#define BB 2
#define NN 16384
#define MM 2048
#define CC 64
#define SS 32

__device__ __forceinline__ float dist2(float qx, float qy, float qz,
                                       float px, float py, float pz) {
    // Match reference rounding: explicit mul/add, no FMA contraction.
    float dx = __fsub_rn(qx, px), dy = __fsub_rn(qy, py), dz = __fsub_rn(qz, pz);
    return __fadd_rn(__fadd_rn(__fmul_rn(dx, dx), __fmul_rn(dy, dy)), __fmul_rn(dz, dz));
}

// Pack xyz (B,N,3) -> float4 (B,N) for aligned dwordx4 scan loads.
__global__ void prep_xyz4(const float* __restrict__ xyz, float4* __restrict__ xyz4) {
    int i = blockIdx.x * 256 + threadIdx.x;
    if (i < BB * NN) {
        xyz4[i] = make_float4(xyz[3 * i], xyz[3 * i + 1], xyz[3 * i + 2], 0.f);
    }
}

// features (B,C,N) -> feat_t (B,N,C), tiled 32x32 through LDS.
__global__ void transpose_feat(const float* __restrict__ f, float* __restrict__ ft) {
    __shared__ float tile[32][33];
    int b = blockIdx.z, n0 = blockIdx.x * 32, c0 = blockIdx.y * 32;
    int tx = threadIdx.x, ty = threadIdx.y;
#pragma unroll
    for (int k = 0; k < 32; k += 8)
        tile[ty + k][tx] = f[((size_t)(b * CC + c0 + ty + k)) * NN + n0 + tx];
    __syncthreads();
#pragma unroll
    for (int k = 0; k < 32; k += 8)
        ft[((size_t)(b * NN + n0 + ty + k)) * CC + c0 + tx] = tile[tx][ty + k];
}

// One wave (64 lanes) per query point. Phase 1: ordered ballot scan over 256
// points/iter (four float4 loads in flight) with wave-uniform early exit.
// Phase 2: gather features (float4 rows from transposed copy, staged in LDS)
// and write channel-major coalesced output.
template <bool FAST>
__global__ __launch_bounds__(64) void query_group(
    const float* __restrict__ xyz, const float* __restrict__ new_xyz,
    const float* __restrict__ features, const float* __restrict__ feat_t,
    const float4* __restrict__ xyz4, float* __restrict__ out) {
    constexpr float R_IN2 = 0.05f * 0.05f;
    constexpr float R_OUT2 = 0.2f * 0.2f;
    __shared__ int idxS[SS];
    __shared__ float fbuf[SS][CC + 4];  // row stride 68 floats: 16B-aligned rows

    int lane = threadIdx.x;
    int bm = blockIdx.x;
    int b = bm >> 11;    // / MM
    int m = bm & 2047;   // % MM

    float qx = new_xyz[(size_t)bm * 3 + 0];
    float qy = new_xyz[(size_t)bm * 3 + 1];
    float qz = new_xyz[(size_t)bm * 3 + 2];

    if (lane == 0) idxS[0] = 0;  // default when zero matches

    unsigned long long below = (1ull << lane) - 1ull;
    int cnt = 0;
    for (int j0 = 0; j0 < NN; j0 += 256) {
        float px[4], py[4], pz[4];
        if (FAST) {
            const float4* base = xyz4 + b * NN + j0 + lane;
#pragma unroll
            for (int u = 0; u < 4; ++u) {
                float4 p = base[u * 64];
                px[u] = p.x; py[u] = p.y; pz[u] = p.z;
            }
        } else {
            const float* pp = xyz + ((size_t)(b * NN + j0 + lane)) * 3;
#pragma unroll
            for (int u = 0; u < 4; ++u) {
                px[u] = pp[u * 192 + 0];
                py[u] = pp[u * 192 + 1];
                pz[u] = pp[u * 192 + 2];
            }
        }
#pragma unroll
        for (int u = 0; u < 4; ++u) {
            float d2 = dist2(qx, qy, qz, px[u], py[u], pz[u]);
            bool inshell = (d2 >= R_IN2) && (d2 < R_OUT2);
            unsigned long long mk = __ballot(inshell);
            if (inshell) {
                int r = cnt + __popcll(mk & below);
                if (r < SS) idxS[r] = j0 + u * 64 + lane;
            }
            cnt += __popcll(mk);
        }
        if (cnt >= SS) break;  // wave-uniform
    }
    if (cnt > SS) cnt = SS;
    if (lane == 0) out[bm] = (float)cnt;  // idx_cnt as float
    __syncthreads();

    float* gout = out + BB * MM;

    if (FAST) {
        // Stage 32 slots x 64 channels into LDS: 16 lanes x float4 per slot,
        // 4 slots per iteration -> fully-used 64B lines from feat_t.
        int s4 = lane >> 4, c4 = lane & 15;
#pragma unroll
        for (int it = 0; it < 8; ++it) {
            int sl = it * 4 + s4;
            int j = (sl < cnt) ? idxS[sl] : idxS[0];
            const float4* src = (const float4*)(feat_t + ((size_t)b * NN + j) * CC);
            float4 v = src[c4];
            *((float4*)&fbuf[sl][c4 * 4]) = v;
        }
        __syncthreads();
    }

    int s = lane & 31, half = lane >> 5;
    int j = (s < cnt) ? idxS[s] : idxS[0];

    float px, py, pz;
    if (FAST) {
        float4 p = xyz4[b * NN + j];
        px = p.x; py = p.y; pz = p.z;
    } else {
        const float* pp = xyz + ((size_t)(b * NN) + j) * 3;
        px = pp[0]; py = pp[1]; pz = pp[2];
    }

    // xyz channels 0..2: grouped_xyz = xyz[j] - new_xyz[m]
    {
        float v01 = half ? __fsub_rn(py, qy) : __fsub_rn(px, qx);
        gout[((size_t)(b * 67 + half) * MM + m) * SS + s] = v01;
        if (half == 0) {
            gout[((size_t)(b * 67 + 2) * MM + m) * SS + s] = __fsub_rn(pz, qz);
        }
    }

    // feature channels: 2 channels per iteration, 32 consecutive slots each ->
    // two contiguous 128B segments per store instruction.
#pragma unroll
    for (int k = 0; k < 32; ++k) {
        int ch = 2 * k + half;
        float v = FAST ? fbuf[s][ch]
                       : features[((size_t)(b * CC + ch)) * NN + j];
        gout[((size_t)(b * 67 + 3 + ch) * MM + m) * SS + s] = v;
    }
}

extern "C" void kernel_launch(void* const* d_in, const int* in_sizes, int n_in,
                              void* d_out, int out_size, void* d_ws, size_t ws_size,
                              hipStream_t stream) {
    const float* xyz = (const float*)d_in[0];
    const float* new_xyz = (const float*)d_in[1];
    const float* features = (const float*)d_in[2];
    float* out = (float*)d_out;

    const size_t featT_bytes = (size_t)BB * NN * CC * 4;  // 8,388,608
    const size_t xyz4_bytes = (size_t)BB * NN * 16;       // 524,288
    bool fast = ws_size >= featT_bytes + xyz4_bytes;

    if (fast) {
        float* feat_t = (float*)d_ws;
        float4* xyz4 = (float4*)((char*)d_ws + featT_bytes);
        prep_xyz4<<<(BB * NN + 255) / 256, 256, 0, stream>>>(xyz, xyz4);
        dim3 tg(NN / 32, CC / 32, BB);
        transpose_feat<<<tg, dim3(32, 8), 0, stream>>>(features, feat_t);
        query_group<true><<<BB * MM, 64, 0, stream>>>(xyz, new_xyz, features, feat_t, xyz4, out);
    } else {
        query_group<false><<<BB * MM, 64, 0, stream>>>(xyz, new_xyz, features, nullptr, nullptr, out);
    }
}

// Round 8
// 92.232 us; speedup vs baseline: 1.0103x; 1.0103x over previous
//
#include <hip/hip_runtime.h>
#include <cstdint>

#define BB 2
#define NN 16384
#define MM 2048
#define CC 64
#define SS 32
#define WPB 4  // waves (queries) per block

__device__ __forceinline__ float dist2(float qx, float qy, float qz,
                                       float px, float py, float pz) {
    // Match reference rounding: explicit mul/add, no FMA contraction.
    // Verified exact (absmax=0.0) in Round 4 — do not change.
    float dx = __fsub_rn(qx, px), dy = __fsub_rn(qy, py), dz = __fsub_rn(qz, pz);
    return __fadd_rn(__fadd_rn(__fmul_rn(dx, dx), __fmul_rn(dy, dy)), __fmul_rn(dz, dz));
}

// Fused prep: blocks [0,2048) transpose features (B,C,N)->(B,N,C) via LDS
// tiles; blocks [2048,2176) pack xyz (B,N,3)->float4. One launch, 256 thr.
__global__ __launch_bounds__(256) void prep_fused(
    const float* __restrict__ xyz, const float* __restrict__ f,
    float* __restrict__ ft, float4* __restrict__ xyz4) {
    int bid = blockIdx.x;
    if (bid < 2048) {
        __shared__ float tile[32][33];
        int n0 = (bid & 511) * 32;          // N/32 = 512 tiles
        int c0 = ((bid >> 9) & 1) * 32;     // C/32 = 2 tiles
        int b = bid >> 10;                  // B = 2
        int tx = threadIdx.x & 31, ty = threadIdx.x >> 5;  // (32,8)
#pragma unroll
        for (int k = 0; k < 32; k += 8)
            tile[ty + k][tx] = f[((size_t)(b * CC + c0 + ty + k)) * NN + n0 + tx];
        __syncthreads();
#pragma unroll
        for (int k = 0; k < 32; k += 8)
            ft[((size_t)(b * NN + n0 + ty + k)) * CC + c0 + tx] = tile[tx][ty + k];
    } else {
        int i = (bid - 2048) * 256 + threadIdx.x;
        if (i < BB * NN) {
            xyz4[i] = make_float4(xyz[3 * i], xyz[3 * i + 1], xyz[3 * i + 2], 0.f);
        }
    }
}

// WPB waves per block, one query per wave. No cross-wave sharing: each wave
// owns its idxS/fbuf slice; all sync is wave-internal lockstep.
// Phase 1: ordered ballot scan, 256 points/iter, wave-uniform early exit.
// Phase 2: feature gather via transposed copy staged in LDS; coalesced
// channel-major stores.
template <bool FAST>
__global__ __launch_bounds__(64 * WPB) void query_group(
    const float* __restrict__ xyz, const float* __restrict__ new_xyz,
    const float* __restrict__ features, const float* __restrict__ feat_t,
    const float4* __restrict__ xyz4, float* __restrict__ out) {
    constexpr float R_IN2 = 0.05f * 0.05f;
    constexpr float R_OUT2 = 0.2f * 0.2f;
    __shared__ int idxS[WPB][SS];
    __shared__ float fbuf[WPB][SS][CC + 4];  // 16B-aligned rows

    int lane = threadIdx.x & 63;
    int w = threadIdx.x >> 6;
    int bm = blockIdx.x * WPB + w;
    int b = bm >> 11;    // / MM
    int m = bm & 2047;   // % MM

    float qx = new_xyz[(size_t)bm * 3 + 0];
    float qy = new_xyz[(size_t)bm * 3 + 1];
    float qz = new_xyz[(size_t)bm * 3 + 2];

    if (lane == 0) idxS[w][0] = 0;  // default when zero matches (wave-lockstep safe)

    unsigned long long below = (1ull << lane) - 1ull;
    int cnt = 0;
    for (int j0 = 0; j0 < NN; j0 += 256) {
        float px[4], py[4], pz[4];
        if (FAST) {
            const float4* base = xyz4 + b * NN + j0 + lane;
#pragma unroll
            for (int u = 0; u < 4; ++u) {
                float4 p = base[u * 64];
                px[u] = p.x; py[u] = p.y; pz[u] = p.z;
            }
        } else {
            const float* pp = xyz + ((size_t)(b * NN + j0 + lane)) * 3;
#pragma unroll
            for (int u = 0; u < 4; ++u) {
                px[u] = pp[u * 192 + 0];
                py[u] = pp[u * 192 + 1];
                pz[u] = pp[u * 192 + 2];
            }
        }
#pragma unroll
        for (int u = 0; u < 4; ++u) {
            float d2 = dist2(qx, qy, qz, px[u], py[u], pz[u]);
            bool inshell = (d2 >= R_IN2) && (d2 < R_OUT2);
            unsigned long long mk = __ballot(inshell);
            if (inshell) {
                int r = cnt + __popcll(mk & below);
                if (r < SS) idxS[w][r] = j0 + u * 64 + lane;
            }
            cnt += __popcll(mk);
        }
        if (cnt >= SS) break;  // wave-uniform
    }
    if (cnt > SS) cnt = SS;
    if (lane == 0) out[bm] = (float)cnt;  // idx_cnt as float

    float* gout = out + BB * MM;

    if (FAST) {
        // Stage 32 slots x 64 channels into this wave's LDS slice:
        // 16 lanes x float4 per slot, 4 slots per iteration.
        int s4 = lane >> 4, c4 = lane & 15;
#pragma unroll
        for (int it = 0; it < 8; ++it) {
            int sl = it * 4 + s4;
            int j = (sl < cnt) ? idxS[w][sl] : idxS[w][0];
            const float4* src = (const float4*)(feat_t + ((size_t)b * NN + j) * CC);
            float4 v = src[c4];
            *((float4*)&fbuf[w][sl][c4 * 4]) = v;
        }
        // wave-internal lockstep: LDS writes by this wave are visible to it
    }

    int s = lane & 31, half = lane >> 5;
    int j = (s < cnt) ? idxS[w][s] : idxS[w][0];

    float px, py, pz;
    if (FAST) {
        float4 p = xyz4[b * NN + j];
        px = p.x; py = p.y; pz = p.z;
    } else {
        const float* pp = xyz + ((size_t)(b * NN) + j) * 3;
        px = pp[0]; py = pp[1]; pz = pp[2];
    }

    // xyz channels 0..2: grouped_xyz = xyz[j] - new_xyz[m]
    {
        float v01 = half ? __fsub_rn(py, qy) : __fsub_rn(px, qx);
        gout[((size_t)(b * 67 + half) * MM + m) * SS + s] = v01;
        if (half == 0) {
            gout[((size_t)(b * 67 + 2) * MM + m) * SS + s] = __fsub_rn(pz, qz);
        }
    }

    // feature channels: 2 channels per iteration, 32 consecutive slots each ->
    // two contiguous 128B segments per store instruction.
#pragma unroll
    for (int k = 0; k < 32; ++k) {
        int ch = 2 * k + half;
        float v = FAST ? fbuf[w][s][ch]
                       : features[((size_t)(b * CC + ch)) * NN + j];
        gout[((size_t)(b * 67 + 3 + ch) * MM + m) * SS + s] = v;
    }
}

extern "C" void kernel_launch(void* const* d_in, const int* in_sizes, int n_in,
                              void* d_out, int out_size, void* d_ws, size_t ws_size,
                              hipStream_t stream) {
    const float* xyz = (const float*)d_in[0];
    const float* new_xyz = (const float*)d_in[1];
    const float* features = (const float*)d_in[2];
    float* out = (float*)d_out;

    const size_t featT_bytes = (size_t)BB * NN * CC * 4;  // 8,388,608
    const size_t xyz4_bytes = (size_t)BB * NN * 16;       // 524,288
    bool fast = ws_size >= featT_bytes + xyz4_bytes;

    if (fast) {
        float* feat_t = (float*)d_ws;
        float4* xyz4 = (float4*)((char*)d_ws + featT_bytes);
        prep_fused<<<2048 + 128, 256, 0, stream>>>(xyz, features, feat_t, xyz4);
        query_group<true><<<BB * MM / WPB, 64 * WPB, 0, stream>>>(xyz, new_xyz, features, feat_t, xyz4, out);
    } else {
        query_group<false><<<BB * MM / WPB, 64 * WPB, 0, stream>>>(xyz, new_xyz, features, nullptr, nullptr, out);
    }
}

// Round 9
// 92.204 us; speedup vs baseline: 1.0106x; 1.0003x over previous
//
#include <hip/hip_runtime.h>
#include <cstdint>

#define BB 2
#define NN 16384
#define MM 2048
#define CC 64
#define SS 32
#define WPB 4  // waves (queries) per block

__device__ __forceinline__ float dist2(float qx, float qy, float qz,
                                       float px, float py, float pz) {
    // Match reference rounding: explicit mul/add, no FMA contraction.
    // Verified exact (absmax=0.0) in Rounds 4/8 — do not change.
    float dx = __fsub_rn(qx, px), dy = __fsub_rn(qy, py), dz = __fsub_rn(qz, pz);
    return __fadd_rn(__fadd_rn(__fmul_rn(dx, dx), __fmul_rn(dy, dy)), __fmul_rn(dz, dz));
}

// Fused prep: blocks [0,2048) transpose features (B,C,N)->(B,N,C) via LDS
// tiles; blocks [2048,2176) pack xyz (B,N,3)->float4. One launch, 256 thr.
__global__ __launch_bounds__(256) void prep_fused(
    const float* __restrict__ xyz, const float* __restrict__ f,
    float* __restrict__ ft, float4* __restrict__ xyz4) {
    int bid = blockIdx.x;
    if (bid < 2048) {
        __shared__ float tile[32][33];
        int n0 = (bid & 511) * 32;          // N/32 = 512 tiles
        int c0 = ((bid >> 9) & 1) * 32;     // C/32 = 2 tiles
        int b = bid >> 10;                  // B = 2
        int tx = threadIdx.x & 31, ty = threadIdx.x >> 5;  // (32,8)
#pragma unroll
        for (int k = 0; k < 32; k += 8)
            tile[ty + k][tx] = f[((size_t)(b * CC + c0 + ty + k)) * NN + n0 + tx];
        __syncthreads();
#pragma unroll
        for (int k = 0; k < 32; k += 8)
            ft[((size_t)(b * NN + n0 + ty + k)) * CC + c0 + tx] = tile[tx][ty + k];
    } else {
        int i = (bid - 2048) * 256 + threadIdx.x;
        if (i < BB * NN) {
            xyz4[i] = make_float4(xyz[3 * i], xyz[3 * i + 1], xyz[3 * i + 2], 0.f);
        }
    }
}

// WPB waves per block, one query per wave. No cross-wave sharing: each wave
// owns its idxS/fbuf slice; all sync is wave-internal lockstep.
// Phase 1: ordered ballot scan, 256 points/iter, wave-uniform early exit.
// Phase 2: ILP gather (8 float4 loads in flight) -> LDS transpose buffer.
// Phase 3: float4 stores, 8 instructions cover all 64 feature channels.
template <bool FAST>
__global__ __launch_bounds__(64 * WPB) void query_group(
    const float* __restrict__ xyz, const float* __restrict__ new_xyz,
    const float* __restrict__ features, const float* __restrict__ feat_t,
    const float4* __restrict__ xyz4, float* __restrict__ out) {
    constexpr float R_IN2 = 0.05f * 0.05f;
    constexpr float R_OUT2 = 0.2f * 0.2f;
    __shared__ int idxS[WPB][SS];
    __shared__ float fbuf[WPB][SS][CC + 4];  // 16B-aligned rows (stride 68)

    int lane = threadIdx.x & 63;
    int w = threadIdx.x >> 6;
    int bm = blockIdx.x * WPB + w;
    int b = bm >> 11;    // / MM
    int m = bm & 2047;   // % MM

    float qx = new_xyz[(size_t)bm * 3 + 0];
    float qy = new_xyz[(size_t)bm * 3 + 1];
    float qz = new_xyz[(size_t)bm * 3 + 2];

    if (lane == 0) idxS[w][0] = 0;  // default when zero matches (wave-lockstep safe)

    unsigned long long below = (1ull << lane) - 1ull;
    int cnt = 0;
    for (int j0 = 0; j0 < NN; j0 += 256) {
        float px[4], py[4], pz[4];
        if (FAST) {
            const float4* base = xyz4 + b * NN + j0 + lane;
#pragma unroll
            for (int u = 0; u < 4; ++u) {
                float4 p = base[u * 64];
                px[u] = p.x; py[u] = p.y; pz[u] = p.z;
            }
        } else {
            const float* pp = xyz + ((size_t)(b * NN + j0 + lane)) * 3;
#pragma unroll
            for (int u = 0; u < 4; ++u) {
                px[u] = pp[u * 192 + 0];
                py[u] = pp[u * 192 + 1];
                pz[u] = pp[u * 192 + 2];
            }
        }
#pragma unroll
        for (int u = 0; u < 4; ++u) {
            float d2 = dist2(qx, qy, qz, px[u], py[u], pz[u]);
            bool inshell = (d2 >= R_IN2) && (d2 < R_OUT2);
            unsigned long long mk = __ballot(inshell);
            if (inshell) {
                int r = cnt + __popcll(mk & below);
                if (r < SS) idxS[w][r] = j0 + u * 64 + lane;
            }
            cnt += __popcll(mk);
        }
        if (cnt >= SS) break;  // wave-uniform
    }
    if (cnt > SS) cnt = SS;
    if (lane == 0) out[bm] = (float)cnt;  // idx_cnt as float

    float* gout = out + BB * MM;

    if (FAST) {
        // Phase 2: gather 32 slots x 64 ch. Lane (s4 = lane>>4, c4 = lane&15):
        // read all 8 slot indices, then 8 independent float4 loads in flight,
        // then 8 LDS writes.
        int s4 = lane >> 4, c4 = lane & 15;
        int jj[8];
#pragma unroll
        for (int it = 0; it < 8; ++it) {
            int sl = it * 4 + s4;
            jj[it] = (sl < cnt) ? idxS[w][sl] : idxS[w][0];
        }
        float4 vv[8];
#pragma unroll
        for (int it = 0; it < 8; ++it)
            vv[it] = ((const float4*)(feat_t + ((size_t)b * NN + jj[it]) * CC))[c4];
#pragma unroll
        for (int it = 0; it < 8; ++it)
            *((float4*)&fbuf[w][it * 4 + s4][c4 * 4]) = vv[it];
        // wave-internal lockstep: this wave's LDS writes are visible to it
    }

    // xyz channels 0..2: grouped_xyz = xyz[j] - new_xyz[m]
    {
        int s = lane & 31, half = lane >> 5;
        int j = (s < cnt) ? idxS[w][s] : idxS[w][0];
        float px, py, pz;
        if (FAST) {
            float4 p = xyz4[b * NN + j];
            px = p.x; py = p.y; pz = p.z;
        } else {
            const float* pp = xyz + ((size_t)(b * NN) + j) * 3;
            px = pp[0]; py = pp[1]; pz = pp[2];
        }
        float v01 = half ? __fsub_rn(py, qy) : __fsub_rn(px, qx);
        gout[((size_t)(b * 67 + half) * MM + m) * SS + s] = v01;
        if (half == 0) {
            gout[((size_t)(b * 67 + 2) * MM + m) * SS + s] = __fsub_rn(pz, qz);
        }
    }

    // Phase 3: feature channels 0..63. Lane (ch8 = lane>>3, sg = lane&7):
    // each instruction stores float4 (4 slots) for 8 channels -> 8 stores total.
    if (FAST) {
        int ch8 = lane >> 3, sg = lane & 7;
#pragma unroll
        for (int it = 0; it < 8; ++it) {
            int ch = it * 8 + ch8;
            float4 v = make_float4(fbuf[w][sg * 4 + 0][ch], fbuf[w][sg * 4 + 1][ch],
                                   fbuf[w][sg * 4 + 2][ch], fbuf[w][sg * 4 + 3][ch]);
            *((float4*)&gout[((size_t)(b * 67 + 3 + ch) * MM + m) * SS + sg * 4]) = v;
        }
    } else {
        int s = lane & 31, half = lane >> 5;
        int j = (s < cnt) ? idxS[w][s] : idxS[w][0];
#pragma unroll
        for (int k = 0; k < 32; ++k) {
            int ch = 2 * k + half;
            float v = features[((size_t)(b * CC + ch)) * NN + j];
            gout[((size_t)(b * 67 + 3 + ch) * MM + m) * SS + s] = v;
        }
    }
}

extern "C" void kernel_launch(void* const* d_in, const int* in_sizes, int n_in,
                              void* d_out, int out_size, void* d_ws, size_t ws_size,
                              hipStream_t stream) {
    const float* xyz = (const float*)d_in[0];
    const float* new_xyz = (const float*)d_in[1];
    const float* features = (const float*)d_in[2];
    float* out = (float*)d_out;

    const size_t featT_bytes = (size_t)BB * NN * CC * 4;  // 8,388,608
    const size_t xyz4_bytes = (size_t)BB * NN * 16;       // 524,288
    bool fast = ws_size >= featT_bytes + xyz4_bytes;

    if (fast) {
        float* feat_t = (float*)d_ws;
        float4* xyz4 = (float4*)((char*)d_ws + featT_bytes);
        prep_fused<<<2048 + 128, 256, 0, stream>>>(xyz, features, feat_t, xyz4);
        query_group<true><<<BB * MM / WPB, 64 * WPB, 0, stream>>>(xyz, new_xyz, features, feat_t, xyz4, out);
    } else {
        query_group<false><<<BB * MM / WPB, 64 * WPB, 0, stream>>>(xyz, new_xyz, features, nullptr, nullptr, out);
    }
}